// Round 1
// baseline (118.519 us; speedup 1.0000x reference)
//
#include <hip/hip_runtime.h>
#include <math.h>

// Problem constants (from reference)
#define BB 16
#define CC 3
#define OO 32
#define HH 128
#define WW 128
#define KH 5
#define KW 5
#define OH 124
#define OW 124
#define NPIX (OH * OW)          // 15376
#define KF 25.0f                // kh*kw

// ---------------------------------------------------------------------------
// Kernel 1: 5x5 VALID window sums of x and x^2, per (b,c).
// Layout: s1/s2 indexed [(b*C+c)*NPIX + pix], pix = i*OW + j.
// ---------------------------------------------------------------------------
__global__ void win_sums_kernel(const float* __restrict__ x,
                                float* __restrict__ s1,
                                float* __restrict__ s2) {
    int idx = blockIdx.x * blockDim.x + threadIdx.x;
    const int total = BB * CC * NPIX;
    if (idx >= total) return;
    int pix = idx % NPIX;
    int bc  = idx / NPIX;
    int i = pix / OW;
    int j = pix % OW;
    const float* img = x + (size_t)bc * (HH * WW);
    float a = 0.0f, q = 0.0f;
#pragma unroll
    for (int di = 0; di < KH; ++di) {
        const float* row = img + (i + di) * WW + j;
#pragma unroll
        for (int dj = 0; dj < KW; ++dj) {
            float v = row[dj];
            a += v;
            q += v * v;
        }
    }
    s1[idx] = a;
    s2[idx] = q;
}

// ---------------------------------------------------------------------------
// Kernel 2: per-pixel unbiased std over the 512 (b,o) dist values.
// dist[b,o,pix] = sum_c sqrt(max(S2 - 2*w*S1 + 25*w^2, 0))
// Thread per pixel; loop (b,o); coalesced S1/S2 reads across threads.
// Double accumulation for the sum/sumsq (cancellation-safe).
// ---------------------------------------------------------------------------
__global__ void pixel_std_kernel(const float* __restrict__ s1,
                                 const float* __restrict__ s2,
                                 const float* __restrict__ wgt,
                                 float* __restrict__ stdbuf) {
    int pix = blockIdx.x * blockDim.x + threadIdx.x;
    if (pix >= NPIX) return;

    double sum = 0.0, sumsq = 0.0;
    for (int b = 0; b < BB; ++b) {
        float S1c[CC], S2c[CC];
#pragma unroll
        for (int c = 0; c < CC; ++c) {
            S1c[c] = s1[(size_t)(b * CC + c) * NPIX + pix];
            S2c[c] = s2[(size_t)(b * CC + c) * NPIX + pix];
        }
#pragma unroll 4
        for (int o = 0; o < OO; ++o) {
            float d = 0.0f;
#pragma unroll
            for (int c = 0; c < CC; ++c) {
                float w = wgt[o * CC + c];
                float inner = S2c[c] - 2.0f * w * S1c[c] + KF * w * w;
                d += sqrtf(fmaxf(inner, 0.0f));
            }
            sum += (double)d;
            sumsq += (double)d * (double)d;
        }
    }
    const double n = (double)(BB * OO);
    double mean = sum / n;
    double var = (sumsq - n * mean * mean) / (n - 1.0);
    if (var < 0.0) var = 0.0;
    stdbuf[pix] = (float)sqrt(var);
}

// ---------------------------------------------------------------------------
// Kernel 3: final output. Thread per (b,o,pix) element of out (b,o,i,j) flat.
// Recomputes dist from S1/S2 (L2-resident), reads per-pixel std, writes exp.
// ---------------------------------------------------------------------------
__global__ void final_out_kernel(const float* __restrict__ s1,
                                 const float* __restrict__ s2,
                                 const float* __restrict__ wgt,
                                 const float* __restrict__ stdbuf,
                                 float* __restrict__ out) {
    int idx = blockIdx.x * blockDim.x + threadIdx.x;
    const int total = BB * OO * NPIX;
    if (idx >= total) return;
    int pix = idx % NPIX;
    int bo  = idx / NPIX;
    int o = bo % OO;
    int b = bo / OO;

    float d = 0.0f;
#pragma unroll
    for (int c = 0; c < CC; ++c) {
        float w  = wgt[o * CC + c];
        float S1 = s1[(size_t)(b * CC + c) * NPIX + pix];
        float S2 = s2[(size_t)(b * CC + c) * NPIX + pix];
        float inner = S2 - 2.0f * w * S1 + KF * w * w;
        d += sqrtf(fmaxf(inner, 0.0f));
    }
    float sd = stdbuf[pix];
    float z = d / sd;
    out[idx] = __expf(-0.5f * z * z);
}

// ---------------------------------------------------------------------------
extern "C" void kernel_launch(void* const* d_in, const int* in_sizes, int n_in,
                              void* d_out, int out_size, void* d_ws, size_t ws_size,
                              hipStream_t stream) {
    const float* x   = (const float*)d_in[0];   // (16,3,128,128)
    const float* wgt = (const float*)d_in[1];   // (32,3)
    float* out = (float*)d_out;                 // (16,32,124,124)

    // Workspace layout (floats): s1 [B*C*NPIX] | s2 [B*C*NPIX] | std [NPIX]
    float* s1  = (float*)d_ws;
    float* s2  = s1 + (size_t)BB * CC * NPIX;
    float* std_ = s2 + (size_t)BB * CC * NPIX;

    {
        int total = BB * CC * NPIX;
        int block = 256;
        int grid = (total + block - 1) / block;
        win_sums_kernel<<<grid, block, 0, stream>>>(x, s1, s2);
    }
    {
        int block = 256;
        int grid = (NPIX + block - 1) / block;
        pixel_std_kernel<<<grid, block, 0, stream>>>(s1, s2, wgt, std_);
    }
    {
        int total = BB * OO * NPIX;
        int block = 256;
        int grid = (total + block - 1) / block;
        final_out_kernel<<<grid, block, 0, stream>>>(s1, s2, wgt, std_, out);
    }
}

// Round 2
// 34.149 us; speedup vs baseline: 3.4706x; 3.4706x over previous
//
#include <hip/hip_runtime.h>
#include <math.h>

// Problem constants (from reference)
#define BB 16
#define CC 3
#define OO 32
#define HH 128
#define WW 128
#define KH 5
#define KW 5
#define OH 124
#define OW 124
#define NPIX (OH * OW)          // 15376
#define KF 25.0f                // kh*kw

#if defined(__has_builtin)
#if __has_builtin(__builtin_amdgcn_sqrtf)
#define FSQRT(x) __builtin_amdgcn_sqrtf(x)
#else
#define FSQRT(x) sqrtf(x)
#endif
#else
#define FSQRT(x) sqrtf(x)
#endif

// ---------------------------------------------------------------------------
// Kernel 1: 5x5 VALID window sums of x and x^2, per (b,c).
// Layout: s1/s2 indexed [(b*C+c)*NPIX + pix], pix = i*OW + j.
// ---------------------------------------------------------------------------
__global__ void win_sums_kernel(const float* __restrict__ x,
                                float* __restrict__ s1,
                                float* __restrict__ s2) {
    int idx = blockIdx.x * blockDim.x + threadIdx.x;
    const int total = BB * CC * NPIX;
    if (idx >= total) return;
    int pix = idx % NPIX;
    int bc  = idx / NPIX;
    int i = pix / OW;
    int j = pix % OW;
    const float* img = x + (size_t)bc * (HH * WW);
    float a = 0.0f, q = 0.0f;
#pragma unroll
    for (int di = 0; di < KH; ++di) {
        const float* row = img + (i + di) * WW + j;
#pragma unroll
        for (int dj = 0; dj < KW; ++dj) {
            float v = row[dj];
            a += v;
            q += v * v;
        }
    }
    s1[idx] = a;
    s2[idx] = q;
}

// ---------------------------------------------------------------------------
// Kernel 2a: partial reduction over o for each (b,pix).
// psum/psq layout [b*NPIX + pix] -> coalesced.
// dist[b,o,pix] = sum_c sqrt(max(S2 - 2*w*S1 + 25*w^2, 0))
// ---------------------------------------------------------------------------
__global__ void partial_kernel(const float* __restrict__ s1,
                               const float* __restrict__ s2,
                               const float* __restrict__ wgt,
                               float* __restrict__ psum,
                               float* __restrict__ psq) {
    int idx = blockIdx.x * blockDim.x + threadIdx.x;
    const int total = BB * NPIX;
    if (idx >= total) return;
    int pix = idx % NPIX;
    int b   = idx / NPIX;

    float S1c[CC], S2c[CC];
#pragma unroll
    for (int c = 0; c < CC; ++c) {
        S1c[c] = s1[(size_t)(b * CC + c) * NPIX + pix];
        S2c[c] = s2[(size_t)(b * CC + c) * NPIX + pix];
    }
    float sum = 0.0f, sumsq = 0.0f;
#pragma unroll 8
    for (int o = 0; o < OO; ++o) {
        float d = 0.0f;
#pragma unroll
        for (int c = 0; c < CC; ++c) {
            float w = wgt[o * CC + c];   // uniform index -> scalar load
            float inner = S2c[c] - 2.0f * w * S1c[c] + KF * w * w;
            d += FSQRT(fmaxf(inner, 0.0f));
        }
        sum += d;
        sumsq += d * d;
    }
    psum[idx] = sum;
    psq[idx]  = sumsq;
}

// ---------------------------------------------------------------------------
// Kernel 2b: finish per-pixel unbiased std over 16 b-partials (double acc).
// ---------------------------------------------------------------------------
__global__ void std_finish_kernel(const float* __restrict__ psum,
                                  const float* __restrict__ psq,
                                  float* __restrict__ stdbuf) {
    int pix = blockIdx.x * blockDim.x + threadIdx.x;
    if (pix >= NPIX) return;
    double sum = 0.0, sumsq = 0.0;
#pragma unroll
    for (int b = 0; b < BB; ++b) {
        sum   += (double)psum[b * NPIX + pix];
        sumsq += (double)psq[b * NPIX + pix];
    }
    const double n = (double)(BB * OO);
    double mean = sum / n;
    double var = (sumsq - n * mean * mean) / (n - 1.0);
    if (var < 0.0) var = 0.0;
    stdbuf[pix] = (float)sqrt(var);
}

// ---------------------------------------------------------------------------
// Kernel 3: final output. Thread per (b,pix), loop over o.
// Loads S1/S2/std once; each o-iteration's store is coalesced.
// ---------------------------------------------------------------------------
__global__ void final_out_kernel(const float* __restrict__ s1,
                                 const float* __restrict__ s2,
                                 const float* __restrict__ wgt,
                                 const float* __restrict__ stdbuf,
                                 float* __restrict__ out) {
    int idx = blockIdx.x * blockDim.x + threadIdx.x;
    const int total = BB * NPIX;
    if (idx >= total) return;
    int pix = idx % NPIX;
    int b   = idx / NPIX;

    float S1c[CC], S2c[CC];
#pragma unroll
    for (int c = 0; c < CC; ++c) {
        S1c[c] = s1[(size_t)(b * CC + c) * NPIX + pix];
        S2c[c] = s2[(size_t)(b * CC + c) * NPIX + pix];
    }
    float inv_sd = 1.0f / stdbuf[pix];

#pragma unroll 8
    for (int o = 0; o < OO; ++o) {
        float d = 0.0f;
#pragma unroll
        for (int c = 0; c < CC; ++c) {
            float w = wgt[o * CC + c];
            float inner = S2c[c] - 2.0f * w * S1c[c] + KF * w * w;
            d += FSQRT(fmaxf(inner, 0.0f));
        }
        float z = d * inv_sd;
        out[(size_t)(b * OO + o) * NPIX + pix] = __expf(-0.5f * z * z);
    }
}

// ---------------------------------------------------------------------------
extern "C" void kernel_launch(void* const* d_in, const int* in_sizes, int n_in,
                              void* d_out, int out_size, void* d_ws, size_t ws_size,
                              hipStream_t stream) {
    const float* x   = (const float*)d_in[0];   // (16,3,128,128)
    const float* wgt = (const float*)d_in[1];   // (32,3)
    float* out = (float*)d_out;                 // (16,32,124,124)

    // Workspace (floats): s1 [B*C*NPIX] | s2 [B*C*NPIX] | psum [B*NPIX]
    //                     | psq [B*NPIX] | std [NPIX]   (~9 MB total)
    float* s1   = (float*)d_ws;
    float* s2   = s1 + (size_t)BB * CC * NPIX;
    float* psum = s2 + (size_t)BB * CC * NPIX;
    float* psq  = psum + (size_t)BB * NPIX;
    float* std_ = psq + (size_t)BB * NPIX;

    {
        int total = BB * CC * NPIX;
        int block = 256;
        win_sums_kernel<<<(total + block - 1) / block, block, 0, stream>>>(x, s1, s2);
    }
    {
        int total = BB * NPIX;
        int block = 256;
        partial_kernel<<<(total + block - 1) / block, block, 0, stream>>>(s1, s2, wgt, psum, psq);
    }
    {
        int block = 256;
        std_finish_kernel<<<(NPIX + block - 1) / block, block, 0, stream>>>(psum, psq, std_);
    }
    {
        int total = BB * NPIX;
        int block = 256;
        final_out_kernel<<<(total + block - 1) / block, block, 0, stream>>>(s1, s2, wgt, std_, out);
    }
}

// Round 3
// 33.005 us; speedup vs baseline: 3.5909x; 1.0347x over previous
//
#include <hip/hip_runtime.h>
#include <math.h>

// Problem constants (from reference)
#define BB 16
#define CC 3
#define OO 32
#define HH 128
#define WW 128
#define OH 124
#define OW 124
#define NPIX (OH * OW)          // 15376
#define NG   (NPIX / 4)         // 3844 4-pixel groups
#define GW   (OW / 4)           // 31 groups per output row
#define KF 25.0f

#if defined(__has_builtin)
#if __has_builtin(__builtin_amdgcn_sqrtf)
#define FSQRT(x) __builtin_amdgcn_sqrtf(x)
#else
#define FSQRT(x) sqrtf(x)
#endif
#else
#define FSQRT(x) sqrtf(x)
#endif

// ---------------------------------------------------------------------------
// Kernel 1: fused window-sums + per-(b,pix) o-reduction.
// Thread per (b, 4-pixel group). Computes S1/S2 for all 3 channels from x
// via float4 row loads + rolling 5-wide window sums; writes s1/s2 (for the
// final kernel) and psum/psq partials for the std.
// ---------------------------------------------------------------------------
__global__ void fused_win_partial(const float* __restrict__ x,
                                  const float* __restrict__ wgt,
                                  float* __restrict__ s1,
                                  float* __restrict__ s2,
                                  float* __restrict__ psum,
                                  float* __restrict__ psq) {
    int idx = blockIdx.x * blockDim.x + threadIdx.x;
    if (idx >= BB * NG) return;
    int g = idx % NG;
    int b = idx / NG;
    int i  = g / GW;
    int j0 = (g % GW) * 4;
    int pixb = i * OW + j0;            // float4-aligned (OW%4==0, j0%4==0)

    float S1c[CC][4], S2c[CC][4];
#pragma unroll
    for (int c = 0; c < CC; ++c) {
#pragma unroll
        for (int t = 0; t < 4; ++t) { S1c[c][t] = 0.0f; S2c[c][t] = 0.0f; }
        const float* img = x + (size_t)(b * CC + c) * (HH * WW);
#pragma unroll
        for (int di = 0; di < 5; ++di) {
            const float4* rp = reinterpret_cast<const float4*>(img + (i + di) * WW + j0);
            float4 lo = rp[0], hi = rp[1];
            float v[8] = {lo.x, lo.y, lo.z, lo.w, hi.x, hi.y, hi.z, hi.w};
            float q[8];
#pragma unroll
            for (int k = 0; k < 8; ++k) q[k] = v[k] * v[k];
            float r  = v[0] + v[1] + v[2] + v[3] + v[4];
            float rq = q[0] + q[1] + q[2] + q[3] + q[4];
            S1c[c][0] += r;  S2c[c][0] += rq;
#pragma unroll
            for (int t = 1; t < 4; ++t) {
                r  += v[t + 4] - v[t - 1];
                rq += q[t + 4] - q[t - 1];
                S1c[c][t] += r;  S2c[c][t] += rq;
            }
        }
    }

    // store S1/S2 for the final kernel
#pragma unroll
    for (int c = 0; c < CC; ++c) {
        float4 a  = {S1c[c][0], S1c[c][1], S1c[c][2], S1c[c][3]};
        float4 qq = {S2c[c][0], S2c[c][1], S2c[c][2], S2c[c][3]};
        *reinterpret_cast<float4*>(&s1[(size_t)(b * CC + c) * NPIX + pixb]) = a;
        *reinterpret_cast<float4*>(&s2[(size_t)(b * CC + c) * NPIX + pixb]) = qq;
    }

    // o-reduction: per-pixel partial sum/sumsq of dist over o (this b)
    float sum[4] = {0, 0, 0, 0}, sq[4] = {0, 0, 0, 0};
#pragma unroll 8
    for (int o = 0; o < OO; ++o) {
        float d[4] = {0, 0, 0, 0};
#pragma unroll
        for (int c = 0; c < CC; ++c) {
            float w  = wgt[o * CC + c];      // uniform -> scalar load
            float tw = 2.0f * w;
            float kw = KF * w * w;
#pragma unroll
            for (int t = 0; t < 4; ++t) {
                float inner = S2c[c][t] - tw * S1c[c][t] + kw;
                d[t] += FSQRT(fmaxf(inner, 0.0f));
            }
        }
#pragma unroll
        for (int t = 0; t < 4; ++t) { sum[t] += d[t]; sq[t] += d[t] * d[t]; }
    }
    float4 fs = {sum[0], sum[1], sum[2], sum[3]};
    float4 fq = {sq[0], sq[1], sq[2], sq[3]};
    *reinterpret_cast<float4*>(&psum[(size_t)b * NPIX + pixb]) = fs;
    *reinterpret_cast<float4*>(&psq [(size_t)b * NPIX + pixb]) = fq;
}

// ---------------------------------------------------------------------------
// Kernel 2: final output. Thread per (b, 4-pixel group); recomputes the
// per-pixel std from psum/psq (double, duplicated across the 16 b-threads,
// all L2-hits), re-reads S1/S2, loops o, float4 stores.
// ---------------------------------------------------------------------------
__global__ void final_kernel(const float* __restrict__ s1,
                             const float* __restrict__ s2,
                             const float* __restrict__ wgt,
                             const float* __restrict__ psum,
                             const float* __restrict__ psq,
                             float* __restrict__ out) {
    int idx = blockIdx.x * blockDim.x + threadIdx.x;
    if (idx >= BB * NG) return;
    int g = idx % NG;
    int b = idx / NG;
    int i  = g / GW;
    int j0 = (g % GW) * 4;
    int pixb = i * OW + j0;

    // per-pixel std over all 512 (b,o) values (double acc, cancellation-safe)
    double sm[4] = {0, 0, 0, 0}, sQ[4] = {0, 0, 0, 0};
#pragma unroll
    for (int bb = 0; bb < BB; ++bb) {
        float4 a = *reinterpret_cast<const float4*>(&psum[(size_t)bb * NPIX + pixb]);
        float4 q = *reinterpret_cast<const float4*>(&psq [(size_t)bb * NPIX + pixb]);
        sm[0] += a.x; sm[1] += a.y; sm[2] += a.z; sm[3] += a.w;
        sQ[0] += q.x; sQ[1] += q.y; sQ[2] += q.z; sQ[3] += q.w;
    }
    float inv_sd[4];
    const double n = (double)(BB * OO);
#pragma unroll
    for (int t = 0; t < 4; ++t) {
        double mean = sm[t] / n;
        double var = (sQ[t] - n * mean * mean) / (n - 1.0);
        if (var < 0.0) var = 0.0;
        inv_sd[t] = (float)(1.0 / sqrt(var));
    }

    float S1c[CC][4], S2c[CC][4];
#pragma unroll
    for (int c = 0; c < CC; ++c) {
        float4 a = *reinterpret_cast<const float4*>(&s1[(size_t)(b * CC + c) * NPIX + pixb]);
        float4 q = *reinterpret_cast<const float4*>(&s2[(size_t)(b * CC + c) * NPIX + pixb]);
        S1c[c][0] = a.x; S1c[c][1] = a.y; S1c[c][2] = a.z; S1c[c][3] = a.w;
        S2c[c][0] = q.x; S2c[c][1] = q.y; S2c[c][2] = q.z; S2c[c][3] = q.w;
    }

#pragma unroll 8
    for (int o = 0; o < OO; ++o) {
        float d[4] = {0, 0, 0, 0};
#pragma unroll
        for (int c = 0; c < CC; ++c) {
            float w  = wgt[o * CC + c];
            float tw = 2.0f * w;
            float kw = KF * w * w;
#pragma unroll
            for (int t = 0; t < 4; ++t) {
                float inner = S2c[c][t] - tw * S1c[c][t] + kw;
                d[t] += FSQRT(fmaxf(inner, 0.0f));
            }
        }
        float4 r;
        float z0 = d[0] * inv_sd[0]; r.x = __expf(-0.5f * z0 * z0);
        float z1 = d[1] * inv_sd[1]; r.y = __expf(-0.5f * z1 * z1);
        float z2 = d[2] * inv_sd[2]; r.z = __expf(-0.5f * z2 * z2);
        float z3 = d[3] * inv_sd[3]; r.w = __expf(-0.5f * z3 * z3);
        *reinterpret_cast<float4*>(&out[(size_t)(b * OO + o) * NPIX + pixb]) = r;
    }
}

// ---------------------------------------------------------------------------
extern "C" void kernel_launch(void* const* d_in, const int* in_sizes, int n_in,
                              void* d_out, int out_size, void* d_ws, size_t ws_size,
                              hipStream_t stream) {
    const float* x   = (const float*)d_in[0];   // (16,3,128,128)
    const float* wgt = (const float*)d_in[1];   // (32,3)
    float* out = (float*)d_out;                 // (16,32,124,124)

    // Workspace (floats): s1 [B*C*NPIX] | s2 [B*C*NPIX] | psum [B*NPIX] | psq [B*NPIX]
    float* s1   = (float*)d_ws;
    float* s2   = s1 + (size_t)BB * CC * NPIX;
    float* psum = s2 + (size_t)BB * CC * NPIX;
    float* psq  = psum + (size_t)BB * NPIX;

    const int total = BB * NG;   // 61504 threads
    const int block = 256;
    const int grid = (total + block - 1) / block;

    fused_win_partial<<<grid, block, 0, stream>>>(x, wgt, s1, s2, psum, psq);
    final_kernel<<<grid, block, 0, stream>>>(s1, s2, wgt, psum, psq, out);
}